// Round 1
// baseline (255.129 us; speedup 1.0000x reference)
//
#include <hip/hip_runtime.h>

// Sizes fixed by the problem.
#define Bz 4
#define Nn 8192
#define Dd 512
#define Ll 64
#define Pp 128
#define Ww 64
#define Ss 32
#define NW 4   // number of window starts per segment

// ---------------------------------------------------------------------------
// per-batch coord stats: mean + std(ddof=1)+1e-8 for x and y. 1024 threads.
__global__ __launch_bounds__(1024) void coordstats_k(const float* __restrict__ coords,
                                                     float* __restrict__ cstats) {
    int b = blockIdx.x;
    int tid = threadIdx.x;
    double sx = 0, sy = 0, sxx = 0, syy = 0;
    for (int i = tid; i < Nn; i += 1024) {
        double x = coords[((size_t)b * Nn + i) * 2 + 0];
        double y = coords[((size_t)b * Nn + i) * 2 + 1];
        sx += x; sy += y; sxx += x * x; syy += y * y;
    }
    for (int o = 32; o > 0; o >>= 1) {
        sx  += __shfl_down(sx,  o); sy  += __shfl_down(sy,  o);
        sxx += __shfl_down(sxx, o); syy += __shfl_down(syy, o);
    }
    __shared__ double red[16][4];
    int wv = tid >> 6, lane = tid & 63;
    if (lane == 0) { red[wv][0] = sx; red[wv][1] = sy; red[wv][2] = sxx; red[wv][3] = syy; }
    __syncthreads();
    if (tid == 0) {
        double tx = 0, ty = 0, txx = 0, tyy = 0;
        for (int i = 0; i < 16; ++i) { tx += red[i][0]; ty += red[i][1]; txx += red[i][2]; tyy += red[i][3]; }
        const double N = (double)Nn;
        double mux = tx / N, muy = ty / N;
        double vx = (txx - N * mux * mux) / (N - 1.0);
        double vy = (tyy - N * muy * muy) / (N - 1.0);
        cstats[b * 4 + 0] = (float)mux;
        cstats[b * 4 + 1] = (float)muy;
        cstats[b * 4 + 2] = (float)sqrt(vx) + 1e-8f;
        cstats[b * 4 + 3] = (float)sqrt(vy) + 1e-8f;
    }
}

// ---------------------------------------------------------------------------
// Fused preprocessing: one block per l (64 blocks x 512 threads).
//   q   = z[l] @ Wq^T            (kept in LDS only)
//   QK[l,:] = q @ Wk ; G[l,:] = q @ W2      (direct store, no atomics)
//   qb2[l]  = sum_e q[e]*b2[e] ;  sqk[l] = sum_d QK[l,d]
__global__ __launch_bounds__(512) void prep_k(
    const float* __restrict__ z,  const float* __restrict__ Wq,
    const float* __restrict__ Wk, const float* __restrict__ W2,
    const float* __restrict__ b2,
    float* __restrict__ QK, float* __restrict__ G,
    float* __restrict__ sqk, float* __restrict__ qb2) {
    __shared__ float zs[Dd];
    __shared__ float qs[Dd];
    __shared__ float pQK[4][Dd];
    __shared__ float pG[4][Dd];
    __shared__ float redb[8], redq[8];

    int l = blockIdx.x, tid = threadIdx.x;
    int wv = tid >> 6, lane = tid & 63;

    zs[tid] = z[(size_t)l * Dd + tid];
    __syncthreads();

    // each lane keeps its 8-float slice of z_l
    float zr[8];
#pragma unroll
    for (int j = 0; j < 8; ++j) zr[j] = zs[lane * 8 + j];

    // ---- phase 1: q[d] for d in [wv*64, wv*64+64), two rows per step ----
    for (int i = 0; i < 64; i += 2) {
        int d0 = wv * 64 + i;
        const float4* r0 = (const float4*)&Wq[(size_t)d0 * Dd];
        const float4* r1 = (const float4*)&Wq[(size_t)(d0 + 1) * Dd];
        float4 a0 = r0[lane * 2], a1 = r0[lane * 2 + 1];
        float4 b0 = r1[lane * 2], b1 = r1[lane * 2 + 1];
        float s0 = a0.x * zr[0] + a0.y * zr[1] + a0.z * zr[2] + a0.w * zr[3]
                 + a1.x * zr[4] + a1.y * zr[5] + a1.z * zr[6] + a1.w * zr[7];
        float s1 = b0.x * zr[0] + b0.y * zr[1] + b0.z * zr[2] + b0.w * zr[3]
                 + b1.x * zr[4] + b1.y * zr[5] + b1.z * zr[6] + b1.w * zr[7];
        for (int o = 32; o > 0; o >>= 1) { s0 += __shfl_xor(s0, o); s1 += __shfl_xor(s1, o); }
        if (lane == 0) { qs[d0] = s0; qs[d0 + 1] = s1; }
    }
    __syncthreads();

    // ---- qb2 partial: qb2[l] = sum_e q[e]*b2[e] ----
    {
        float p = qs[tid] * b2[tid];
        for (int o = 32; o > 0; o >>= 1) p += __shfl_xor(p, o);
        if (lane == 0) redb[wv] = p;
    }

    // ---- phase 2: QK = q @ Wk, G = q @ W2. 4 e-groups x 128 d4-columns ----
    int g = tid >> 7, c = tid & 127;
    float4 aq = make_float4(0.f, 0.f, 0.f, 0.f);
    float4 ag = make_float4(0.f, 0.f, 0.f, 0.f);
    for (int e = g * 128; e < g * 128 + 128; ++e) {
        float qe = qs[e];
        float4 wk = *(const float4*)&Wk[(size_t)e * Dd + c * 4];
        float4 w2 = *(const float4*)&W2[(size_t)e * Dd + c * 4];
        aq.x = fmaf(qe, wk.x, aq.x); aq.y = fmaf(qe, wk.y, aq.y);
        aq.z = fmaf(qe, wk.z, aq.z); aq.w = fmaf(qe, wk.w, aq.w);
        ag.x = fmaf(qe, w2.x, ag.x); ag.y = fmaf(qe, w2.y, ag.y);
        ag.z = fmaf(qe, w2.z, ag.z); ag.w = fmaf(qe, w2.w, ag.w);
    }
    *(float4*)&pQK[g][c * 4] = aq;
    *(float4*)&pG[g][c * 4]  = ag;
    __syncthreads();

    float vq = pQK[0][tid] + pQK[1][tid] + pQK[2][tid] + pQK[3][tid];
    float vg = pG[0][tid]  + pG[1][tid]  + pG[2][tid]  + pG[3][tid];
    QK[(size_t)l * Dd + tid] = vq;
    G[(size_t)l * Dd + tid]  = vg;

    {
        float p = vq;
        for (int o = 32; o > 0; o >>= 1) p += __shfl_xor(p, o);
        if (lane == 0) redq[wv] = p;
    }
    __syncthreads();
    if (tid == 0) {
        float a = 0.f, b = 0.f;
        for (int i = 0; i < 8; ++i) { a += redb[i]; b += redq[i]; }
        qb2[l] = a; sqk[l] = b;
    }
}

// ---------------------------------------------------------------------------
// Direct-store full-K GEMM: C[m,n] = sum_k A[m,k]*B[n,k] (+ bias[n]).
// 64x32 tile per block, K looped in 64-steps. No atomics, no pre-zero.
__global__ __launch_bounds__(256) void gemmf(
    const float* __restrict__ A, const float* __restrict__ B,
    const float* __restrict__ bias, float* __restrict__ C,
    int N, int K) {
    __shared__ float As[64][68];
    __shared__ float Bs[64][36];
    int tid = threadIdx.x;
    int n0 = blockIdx.x * 32;
    int m0 = blockIdx.y * 64;
    int tx = tid & 31, ty = tid >> 5;
    float acc[8] = {0.f, 0.f, 0.f, 0.f, 0.f, 0.f, 0.f, 0.f};

    for (int k0 = 0; k0 < K; k0 += 64) {
        {
            int r = tid >> 4, c4 = (tid & 15) * 4;
#pragma unroll
            for (int i = 0; i < 4; ++i) {
                const float4 v = *(const float4*)&A[(size_t)(m0 + r + 16 * i) * K + k0 + c4];
                *(float4*)&As[r + 16 * i][c4] = v;
            }
#pragma unroll
            for (int i = 0; i < 2; ++i) {
                int nn = r + 16 * i;
                const float4 v = *(const float4*)&B[(size_t)(n0 + nn) * K + k0 + c4];
                Bs[c4 + 0][nn] = v.x; Bs[c4 + 1][nn] = v.y;
                Bs[c4 + 2][nn] = v.z; Bs[c4 + 3][nn] = v.w;
            }
        }
        __syncthreads();
#pragma unroll 16
        for (int kk = 0; kk < 64; ++kk) {
            float bv = Bs[kk][tx];
#pragma unroll
            for (int i = 0; i < 8; ++i)
                acc[i] = fmaf(As[ty + 8 * i][kk], bv, acc[i]);
        }
        __syncthreads();
    }
    float bb = (bias != nullptr) ? bias[n0 + tx] : 0.f;
#pragma unroll
    for (int i = 0; i < 8; ++i)
        C[(size_t)(m0 + ty + 8 * i) * N + n0 + tx] = acc[i] + bb;
}

// ---------------------------------------------------------------------------
// Fused attention: one block per (b,l). Pass 1 over the segment's 128 rows
// computes per-row (mu, rs, a=QK.f) — absorbs rowstats. Middle: per-window
// pos-bias + softmax from LDS scalars. Pass 2: single combined weighted
// feature sum (windows' weights merged per row), direct store (no atomics).
__global__ __launch_bounds__(512) void attn2(
    const float* __restrict__ feats, const float* __restrict__ coords,
    const float* __restrict__ cstats,
    const float* __restrict__ QKm, const float* __restrict__ Gm,
    const float* __restrict__ sqk, const float* __restrict__ qb2,
    const float* __restrict__ W1, const float* __restrict__ b1,
    float* __restrict__ fmean) {
    __shared__ float  qk_s[Dd];
    __shared__ float4 wpack[Dd];            // {w1a, w1b, b1, g}
    __shared__ float  scx[Pp], scy[Pp];
    __shared__ float  smu[Pp], srs[Pp], sa[Pp];
    __shared__ float  shs[NW * Ww];
    __shared__ float  sar[NW][Ww];
    __shared__ float  swt[Pp];
    __shared__ float  scm[8];               // cmx[4], cmy[4]
    __shared__ float  s2red[NW];
    __shared__ float  soff;
    __shared__ float  spart[4][Dd];

    int bx = blockIdx.x;                    // b*64 + l
    int l = bx & 63, b = bx >> 6;
    int tid = threadIdx.x;
    int wv = tid >> 6, lane = tid & 63;

    // ---- prologue ----
    qk_s[tid]  = QKm[l * Dd + tid];
    wpack[tid] = make_float4(W1[2 * tid], W1[2 * tid + 1], b1[tid], Gm[l * Dd + tid]);
    if (tid < Pp) {
        int row = bx * Pp + tid;
        float x = coords[(size_t)row * 2], y = coords[(size_t)row * 2 + 1];
        scx[tid] = (x - cstats[b * 4 + 0]) / cstats[b * 4 + 2];
        scy[tid] = (y - cstats[b * 4 + 1]) / cstats[b * 4 + 3];
    }
    float sqk_l = sqk[l], qb2_l = qb2[l];
    __syncthreads();

    // window coord means (waves 0..3)
    if (wv < 4) {
        int n = wv, w = lane;
        int nv = (n == 3) ? 32 : 64;
        float cx = (w < nv) ? scx[n * Ss + w] : 0.f;
        float cy = (w < nv) ? scy[n * Ss + w] : 0.f;
        for (int o = 32; o > 0; o >>= 1) { cx += __shfl_xor(cx, o); cy += __shfl_xor(cy, o); }
        if (lane == 0) { scm[n] = cx / (float)nv; scm[4 + n] = cy / (float)nv; }
    }

    // ---- pass 1: per-row mu, rs, a (one HBM pass over 128 rows) ----
    const float* fbase = feats + (size_t)bx * Pp * Dd;
    float4 q0 = ((const float4*)qk_s)[lane];
    float4 q1 = ((const float4*)qk_s)[lane + 64];
#pragma unroll 2
    for (int i = 0; i < 16; ++i) {
        int r = wv * 16 + i;
        const float4* fr = (const float4*)(fbase + (size_t)r * Dd);
        float4 v0 = fr[lane];
        float4 v1 = fr[lane + 64];
        float s  = v0.x + v0.y + v0.z + v0.w + v1.x + v1.y + v1.z + v1.w;
        float ss = v0.x * v0.x + v0.y * v0.y + v0.z * v0.z + v0.w * v0.w
                 + v1.x * v1.x + v1.y * v1.y + v1.z * v1.z + v1.w * v1.w;
        float a  = v0.x * q0.x + v0.y * q0.y + v0.z * q0.z + v0.w * q0.w
                 + v1.x * q1.x + v1.y * q1.y + v1.z * q1.z + v1.w * q1.w;
        for (int o = 32; o > 0; o >>= 1) {
            s += __shfl_xor(s, o); ss += __shfl_xor(ss, o); a += __shfl_xor(a, o);
        }
        if (lane == 0) {
            float mu  = s * (1.f / (float)Dd);
            float var = ss * (1.f / (float)Dd) - mu * mu;
            smu[r] = mu; srs[r] = 1.f / sqrtf(var + 1e-5f); sa[r] = a;
        }
    }
    __syncthreads();

    // ---- pos-bias hs per (window, slot): 2 lanes per slot, half-D each ----
    {
        int s = tid >> 1, half = tid & 1;
        int n = s >> 6, w = s & 63;
        int nv = (n == 3) ? 32 : 64;
        float hs = 0.f;
        if (w < nv) {
            int p = n * Ss + w;
            float px = scx[p] - scm[n], py = scy[p] - scm[4 + n];
            int d0 = half * 256;
#pragma unroll 4
            for (int d = d0; d < d0 + 256; ++d) {
                float4 c = wpack[d];
                hs = fmaf(c.w, fmaxf(fmaf(c.x, px, fmaf(c.y, py, c.z)), 0.f), hs);
            }
        }
        hs += __shfl_xor(hs, 1);
        if (half == 0) shs[s] = hs;
    }
    __syncthreads();

    // ---- softmax per window (waves 0..3) ----
    const float invtemp = 0.04419417382415922f; // 1/sqrt(512)
    if (wv < 4) {
        int n = wv, w = lane;
        int nv = (n == 3) ? 32 : 64;
        int p = n * Ss + ((w < nv) ? w : 0);
        float lg = -1e30f;
        if (w < nv) {
            lg = (srs[p] * (sa[p] - smu[p] * sqk_l) + shs[n * Ww + w] + qb2_l) * invtemp;
            lg = fminf(fmaxf(lg, -10.f), 10.f);
        }
        float m = lg;
        for (int o = 32; o > 0; o >>= 1) m = fmaxf(m, __shfl_xor(m, o));
        float e = (w < nv) ? expf(lg - m) : 0.f;
        float ssum = e;
        for (int o = 32; o > 0; o >>= 1) ssum += __shfl_xor(ssum, o);
        float ar = (w < nv) ? (e / ssum) * srs[p] : 0.f;
        sar[n][w] = ar;
        float t2 = (w < nv) ? ar * smu[p] : 0.f;
        for (int o = 32; o > 0; o >>= 1) t2 += __shfl_xor(t2, o);
        if (lane == 0) s2red[n] = t2;
    }
    __syncthreads();

    // ---- combine per-row weights across (<=2) covering windows ----
    if (tid < Pp) {
        int p = tid;
        int na = (p >> 5) - 1, nb = (p >> 5);
        float wt = 0.f;
        if (na >= 0 && na <= 3) wt += sar[na][p - na * Ss];
        if (nb <= 3)            wt += sar[nb][p - nb * Ss];
        swt[p] = wt;
    }
    if (tid == 0) soff = 0.25f * (s2red[0] + s2red[1] + s2red[2] + s2red[3]);
    __syncthreads();

    // ---- pass 2: combined weighted feature sum (cache-warm re-read) ----
    {
        int g = tid >> 7, c4 = tid & 127;
        const float4* f4 = (const float4*)fbase;
        float4 acc = make_float4(0.f, 0.f, 0.f, 0.f);
#pragma unroll 4
        for (int p = g; p < Pp; p += 4) {
            float wt = swt[p];
            float4 v = f4[p * 128 + c4];
            acc.x = fmaf(wt, v.x, acc.x);
            acc.y = fmaf(wt, v.y, acc.y);
            acc.z = fmaf(wt, v.z, acc.z);
            acc.w = fmaf(wt, v.w, acc.w);
        }
        *(float4*)&spart[g][c4 * 4] = acc;
    }
    __syncthreads();
    {
        float v = spart[0][tid] + spart[1][tid] + spart[2][tid] + spart[3][tid];
        fmean[(size_t)bx * Dd + tid] = 0.25f * v - soff;
    }
}

// ---------------------------------------------------------------------------
extern "C" void kernel_launch(void* const* d_in, const int* in_sizes, int n_in,
                              void* d_out, int out_size, void* d_ws, size_t ws_size,
                              hipStream_t stream) {
    const float* feats  = (const float*)d_in[0];
    const float* coords = (const float*)d_in[1];
    // d_in[2] = mask, unused (all false, and unused by the reference body)
    const float* z  = (const float*)d_in[3];
    const float* Wq = (const float*)d_in[4];
    const float* Wk = (const float*)d_in[5];
    const float* Wv = (const float*)d_in[6];
    const float* W1 = (const float*)d_in[7];
    const float* b1 = (const float*)d_in[8];
    const float* W2 = (const float*)d_in[9];
    const float* b2 = (const float*)d_in[10];
    const float* Wo = (const float*)d_in[11];
    const float* bo = (const float*)d_in[12];
    float* out = (float*)d_out;

    // workspace layout (floats) — nothing needs pre-zeroing
    float* ws = (float*)d_ws;
    float* cstats = ws;                         // 16
    float* QK     = ws + 16;                    // 64*512
    float* G      = QK + Ll * Dd;               // 64*512
    float* sqk    = G + Ll * Dd;                // 64
    float* qb2    = sqk + Ll;                   // 64
    float* fmean  = qb2 + Ll;                   // 256*512
    float* zl     = fmean + Bz * Ll * Dd;       // 256*512

    coordstats_k<<<Bz, 1024, 0, stream>>>(coords, cstats);
    prep_k<<<Ll, 512, 0, stream>>>(z, Wq, Wk, W2, b2, QK, G, sqk, qb2);

    attn2<<<Bz * Ll, 512, 0, stream>>>(feats, coords, cstats,
                                       QK, G, sqk, qb2, W1, b1, fmean);

    // zl = fmean @ Wv^T ; out = zl @ Wo^T + bo  (direct store, bias fused)
    gemmf<<<dim3(Dd / 32, (Bz * Ll) / 64), 256, 0, stream>>>(
        fmean, Wv, nullptr, zl, Dd, Dd);
    gemmf<<<dim3(Dd / 32, (Bz * Ll) / 64), 256, 0, stream>>>(
        zl, Wo, bo, out, Dd, Dd);
}

// Round 2
// 183.937 us; speedup vs baseline: 1.3870x; 1.3870x over previous
//
#include <hip/hip_runtime.h>

// Sizes fixed by the problem.
#define Bz 4
#define Nn 8192
#define Dd 512
#define Ll 64
#define Pp 128
#define Ww 64
#define Ss 32
#define NW 4   // number of window starts per segment

// ---------------------------------------------------------------------------
// pre_k: ONE kernel, three roles by blockIdx.x (256 threads everywhere):
//   [0,256):   prep — block (l, ch): recompute Q[l,:] (L2-cached Wq),
//              then QK/G 128-col chunk, sqk partial, qb2 (ch==0)
//   [256,384): WvoT = Wv^T @ Wo^T, 64x32 tiles  (WvoT[e][d] = sum_c Wv[c,e]Wo[d,c])
//   [384,388): per-batch coord stats (mean + std ddof=1)
__global__ __launch_bounds__(256) void pre_k(
    const float* __restrict__ coords,
    const float* __restrict__ z,  const float* __restrict__ Wq,
    const float* __restrict__ Wk, const float* __restrict__ W2,
    const float* __restrict__ b2,
    const float* __restrict__ Wv, const float* __restrict__ Wo,
    float* __restrict__ cstats,
    float* __restrict__ QK, float* __restrict__ G,
    float* __restrict__ sqk4, float* __restrict__ qb2,
    float* __restrict__ WvoT) {
    __shared__ float smem[64 * 68 + 64 * 36];   // 26.6 KB, aliased per role
    int bid = blockIdx.x, tid = threadIdx.x;
    int wv = tid >> 6, lane = tid & 63;

    if (bid < 256) {
        // ---------------- prep ----------------
        int l = bid & 63, ch = bid >> 6;        // chunk cols [ch*128, ch*128+128)
        float* qs  = smem;                      // [512]
        float* pq  = smem + 512;                // [1024] (8 x 128)
        float* pg  = smem + 1536;               // [1024]
        float* red = smem + 2560;               // [8]

        float zr[8];
        {
            const float4* zp = (const float4*)&z[(size_t)l * Dd + lane * 8];
            float4 z0 = zp[0], z1 = zp[1];
            zr[0] = z0.x; zr[1] = z0.y; zr[2] = z0.z; zr[3] = z0.w;
            zr[4] = z1.x; zr[5] = z1.y; zr[6] = z1.z; zr[7] = z1.w;
        }
        // phase A: q[d] for wave's 128-row range, 2 rows per iter
        for (int i = 0; i < 128; i += 2) {
            int d0 = wv * 128 + i;
            const float4* r0 = (const float4*)&Wq[(size_t)d0 * Dd];
            const float4* r1 = (const float4*)&Wq[(size_t)(d0 + 1) * Dd];
            float4 a0 = r0[lane * 2], a1 = r0[lane * 2 + 1];
            float4 b0 = r1[lane * 2], b1 = r1[lane * 2 + 1];
            float s0 = a0.x * zr[0] + a0.y * zr[1] + a0.z * zr[2] + a0.w * zr[3]
                     + a1.x * zr[4] + a1.y * zr[5] + a1.z * zr[6] + a1.w * zr[7];
            float s1 = b0.x * zr[0] + b0.y * zr[1] + b0.z * zr[2] + b0.w * zr[3]
                     + b1.x * zr[4] + b1.y * zr[5] + b1.z * zr[6] + b1.w * zr[7];
            for (int o = 32; o > 0; o >>= 1) { s0 += __shfl_xor(s0, o); s1 += __shfl_xor(s1, o); }
            if (lane == 0) { qs[d0] = s0; qs[d0 + 1] = s1; }
        }
        __syncthreads();
        // qb2 partials (ch==0 blocks only): red[4..7]
        if (ch == 0) {
            float p = qs[tid] * b2[tid] + qs[tid + 256] * b2[tid + 256];
            for (int o = 32; o > 0; o >>= 1) p += __shfl_xor(p, o);
            if (lane == 0) red[4 + wv] = p;
        }
        // phase B: QK/G chunk. thread: col-quad qd, e-group h (8 groups of 64)
        {
            int qd = tid & 31, h = tid >> 5;
            int cb = ch * 128 + qd * 4;
            float4 aq = make_float4(0.f, 0.f, 0.f, 0.f);
            float4 ag = make_float4(0.f, 0.f, 0.f, 0.f);
            for (int e = h * 64; e < h * 64 + 64; ++e) {
                float qe = qs[e];
                float4 wk = *(const float4*)&Wk[(size_t)e * Dd + cb];
                float4 w2 = *(const float4*)&W2[(size_t)e * Dd + cb];
                aq.x = fmaf(qe, wk.x, aq.x); aq.y = fmaf(qe, wk.y, aq.y);
                aq.z = fmaf(qe, wk.z, aq.z); aq.w = fmaf(qe, wk.w, aq.w);
                ag.x = fmaf(qe, w2.x, ag.x); ag.y = fmaf(qe, w2.y, ag.y);
                ag.z = fmaf(qe, w2.z, ag.z); ag.w = fmaf(qe, w2.w, ag.w);
            }
            *(float4*)&pq[h * 128 + qd * 4] = aq;
            *(float4*)&pg[h * 128 + qd * 4] = ag;
        }
        __syncthreads();
        if (tid < 128) {
            float vq = 0.f, vg = 0.f;
#pragma unroll
            for (int hh = 0; hh < 8; ++hh) { vq += pq[hh * 128 + tid]; vg += pg[hh * 128 + tid]; }
            QK[(size_t)l * Dd + ch * 128 + tid] = vq;
            G [(size_t)l * Dd + ch * 128 + tid] = vg;
            float s = vq;
            for (int o = 32; o > 0; o >>= 1) s += __shfl_xor(s, o);
            if (lane == 0) red[wv] = s;         // wv in {0,1}
        }
        __syncthreads();
        if (tid == 0) sqk4[ch * 64 + l] = red[0] + red[1];
        if (ch == 0 && tid == 32) qb2[l] = red[4] + red[5] + red[6] + red[7];
    } else if (bid < 384) {
        // ---------------- WvoT tiles ----------------
        int wb = bid - 256;
        int m0 = (wb >> 4) * 64;                // e-base
        int n0 = (wb & 15) * 32;                // d-base
        float (*As)[68] = (float (*)[68])smem;
        float (*Bs)[36] = (float (*)[36])(smem + 64 * 68);
        int tx = tid & 31, ty = tid >> 5;
        float acc[8] = {0.f, 0.f, 0.f, 0.f, 0.f, 0.f, 0.f, 0.f};
        for (int c0 = 0; c0 < Dd; c0 += 64) {
            int r = tid >> 4, c4 = (tid & 15) * 4;
#pragma unroll
            for (int i = 0; i < 4; ++i) {
                int cc = r + 16 * i;
                float4 v = *(const float4*)&Wv[(size_t)(c0 + cc) * Dd + m0 + c4];
                As[c4 + 0][cc] = v.x; As[c4 + 1][cc] = v.y;
                As[c4 + 2][cc] = v.z; As[c4 + 3][cc] = v.w;
            }
#pragma unroll
            for (int i = 0; i < 2; ++i) {
                int nn = r + 16 * i;
                float4 v = *(const float4*)&Wo[(size_t)(n0 + nn) * Dd + c0 + c4];
                Bs[c4 + 0][nn] = v.x; Bs[c4 + 1][nn] = v.y;
                Bs[c4 + 2][nn] = v.z; Bs[c4 + 3][nn] = v.w;
            }
            __syncthreads();
#pragma unroll 16
            for (int kk = 0; kk < 64; ++kk) {
                float bv = Bs[kk][tx];
#pragma unroll
                for (int i = 0; i < 8; ++i)
                    acc[i] = fmaf(As[ty + 8 * i][kk], bv, acc[i]);
            }
            __syncthreads();
        }
#pragma unroll
        for (int i = 0; i < 8; ++i)
            WvoT[(size_t)(m0 + ty + 8 * i) * Dd + n0 + tx] = acc[i];
    } else {
        // ---------------- coord stats ----------------
        int b = bid - 384;
        double sx = 0, sy = 0, sxx = 0, syy = 0;
        const float4* cp = (const float4*)(coords + (size_t)b * Nn * 2);
        for (int i = tid; i < Nn / 2; i += 256) {      // 2 points per float4
            float4 v = cp[i];
            sx  += (double)v.x + (double)v.z;
            sy  += (double)v.y + (double)v.w;
            sxx += (double)v.x * v.x + (double)v.z * v.z;
            syy += (double)v.y * v.y + (double)v.w * v.w;
        }
        for (int o = 32; o > 0; o >>= 1) {
            sx  += __shfl_down(sx,  o); sy  += __shfl_down(sy,  o);
            sxx += __shfl_down(sxx, o); syy += __shfl_down(syy, o);
        }
        double* dred = (double*)smem;
        if (lane == 0) {
            dred[wv * 4 + 0] = sx;  dred[wv * 4 + 1] = sy;
            dred[wv * 4 + 2] = sxx; dred[wv * 4 + 3] = syy;
        }
        __syncthreads();
        if (tid == 0) {
            double tx = 0, ty = 0, txx = 0, tyy = 0;
            for (int i = 0; i < 4; ++i) {
                tx += dred[i * 4 + 0]; ty += dred[i * 4 + 1];
                txx += dred[i * 4 + 2]; tyy += dred[i * 4 + 3];
            }
            const double N = (double)Nn;
            double mux = tx / N, muy = ty / N;
            double vx = (txx - N * mux * mux) / (N - 1.0);
            double vy = (tyy - N * muy * muy) / (N - 1.0);
            cstats[b * 4 + 0] = (float)mux;
            cstats[b * 4 + 1] = (float)muy;
            cstats[b * 4 + 2] = (float)sqrt(vx) + 1e-8f;
            cstats[b * 4 + 3] = (float)sqrt(vy) + 1e-8f;
        }
    }
}

// ---------------------------------------------------------------------------
// Fused attention + output projection: one block per (b,l).
// Pass 1 over the segment's 128 rows computes per-row (mu, rs, a=QK.f).
// Middle: per-window pos-bias + softmax from LDS scalars.
// Pass 2: combined weighted feature sum (L3-warm re-read) -> fmean in LDS.
// Tail: out = fmean @ WvoT + bo (WvoT = (Wo@Wv)^T, L2-resident), direct store.
__global__ __launch_bounds__(512) void attn2(
    const float* __restrict__ feats, const float* __restrict__ coords,
    const float* __restrict__ cstats,
    const float* __restrict__ QKm, const float* __restrict__ Gm,
    const float* __restrict__ sqk4, const float* __restrict__ qb2,
    const float* __restrict__ W1, const float* __restrict__ b1,
    const float* __restrict__ WvoT, const float* __restrict__ bo,
    float* __restrict__ out) {
    __shared__ float  qk_s[Dd];
    __shared__ float4 wpack[Dd];            // {w1a, w1b, b1, g}
    __shared__ float  scx[Pp], scy[Pp];
    __shared__ float  smu[Pp], srs[Pp], sa[Pp];
    __shared__ float  shs[NW * Ww];
    __shared__ float  sar[NW][Ww];
    __shared__ float  swt[Pp];
    __shared__ float  scm[8];               // cmx[4], cmy[4]
    __shared__ float  s2red[NW];
    __shared__ float  soff;
    __shared__ float  spart[4][Dd];
    __shared__ float  fm_s[Dd];

    int bx = blockIdx.x;                    // b*64 + l
    int l = bx & 63, b = bx >> 6;
    int tid = threadIdx.x;
    int wv = tid >> 6, lane = tid & 63;

    // ---- prologue ----
    qk_s[tid]  = QKm[l * Dd + tid];
    wpack[tid] = make_float4(W1[2 * tid], W1[2 * tid + 1], b1[tid], Gm[l * Dd + tid]);
    if (tid < Pp) {
        int row = bx * Pp + tid;
        float x = coords[(size_t)row * 2], y = coords[(size_t)row * 2 + 1];
        scx[tid] = (x - cstats[b * 4 + 0]) / cstats[b * 4 + 2];
        scy[tid] = (y - cstats[b * 4 + 1]) / cstats[b * 4 + 3];
    }
    float sqk_l = sqk4[l] + sqk4[64 + l] + sqk4[128 + l] + sqk4[192 + l];
    float qb2_l = qb2[l];
    __syncthreads();

    // window coord means (waves 0..3)
    if (wv < 4) {
        int n = wv, w = lane;
        int nv = (n == 3) ? 32 : 64;
        float cx = (w < nv) ? scx[n * Ss + w] : 0.f;
        float cy = (w < nv) ? scy[n * Ss + w] : 0.f;
        for (int o = 32; o > 0; o >>= 1) { cx += __shfl_xor(cx, o); cy += __shfl_xor(cy, o); }
        if (lane == 0) { scm[n] = cx / (float)nv; scm[4 + n] = cy / (float)nv; }
    }

    // ---- pass 1: per-row mu, rs, a (one HBM pass over 128 rows) ----
    const float* fbase = feats + (size_t)bx * Pp * Dd;
    float4 q0 = ((const float4*)qk_s)[lane];
    float4 q1 = ((const float4*)qk_s)[lane + 64];
#pragma unroll 2
    for (int i = 0; i < 16; ++i) {
        int r = wv * 16 + i;
        const float4* fr = (const float4*)(fbase + (size_t)r * Dd);
        float4 v0 = fr[lane];
        float4 v1 = fr[lane + 64];
        float s  = v0.x + v0.y + v0.z + v0.w + v1.x + v1.y + v1.z + v1.w;
        float ss = v0.x * v0.x + v0.y * v0.y + v0.z * v0.z + v0.w * v0.w
                 + v1.x * v1.x + v1.y * v1.y + v1.z * v1.z + v1.w * v1.w;
        float a  = v0.x * q0.x + v0.y * q0.y + v0.z * q0.z + v0.w * q0.w
                 + v1.x * q1.x + v1.y * q1.y + v1.z * q1.z + v1.w * q1.w;
        for (int o = 32; o > 0; o >>= 1) {
            s += __shfl_xor(s, o); ss += __shfl_xor(ss, o); a += __shfl_xor(a, o);
        }
        if (lane == 0) {
            float mu  = s * (1.f / (float)Dd);
            float var = ss * (1.f / (float)Dd) - mu * mu;
            smu[r] = mu; srs[r] = 1.f / sqrtf(var + 1e-5f); sa[r] = a;
        }
    }
    __syncthreads();

    // ---- pos-bias hs per (window, slot): 2 lanes per slot, half-D each ----
    {
        int s = tid >> 1, half = tid & 1;
        int n = s >> 6, w = s & 63;
        int nv = (n == 3) ? 32 : 64;
        float hs = 0.f;
        if (w < nv) {
            int p = n * Ss + w;
            float px = scx[p] - scm[n], py = scy[p] - scm[4 + n];
            int d0 = half * 256;
#pragma unroll 4
            for (int d = d0; d < d0 + 256; ++d) {
                float4 c = wpack[d];
                hs = fmaf(c.w, fmaxf(fmaf(c.x, px, fmaf(c.y, py, c.z)), 0.f), hs);
            }
        }
        hs += __shfl_xor(hs, 1);
        if (half == 0) shs[s] = hs;
    }
    __syncthreads();

    // ---- softmax per window (waves 0..3) ----
    const float invtemp = 0.04419417382415922f; // 1/sqrt(512)
    if (wv < 4) {
        int n = wv, w = lane;
        int nv = (n == 3) ? 32 : 64;
        int p = n * Ss + ((w < nv) ? w : 0);
        float lg = -1e30f;
        if (w < nv) {
            lg = (srs[p] * (sa[p] - smu[p] * sqk_l) + shs[n * Ww + w] + qb2_l) * invtemp;
            lg = fminf(fmaxf(lg, -10.f), 10.f);
        }
        float m = lg;
        for (int o = 32; o > 0; o >>= 1) m = fmaxf(m, __shfl_xor(m, o));
        float e = (w < nv) ? expf(lg - m) : 0.f;
        float ssum = e;
        for (int o = 32; o > 0; o >>= 1) ssum += __shfl_xor(ssum, o);
        float ar = (w < nv) ? (e / ssum) * srs[p] : 0.f;
        sar[n][w] = ar;
        float t2 = (w < nv) ? ar * smu[p] : 0.f;
        for (int o = 32; o > 0; o >>= 1) t2 += __shfl_xor(t2, o);
        if (lane == 0) s2red[n] = t2;
    }
    __syncthreads();

    // ---- combine per-row weights across (<=2) covering windows ----
    if (tid < Pp) {
        int p = tid;
        int na = (p >> 5) - 1, nb = (p >> 5);
        float wt = 0.f;
        if (na >= 0 && na <= 3) wt += sar[na][p - na * Ss];
        if (nb <= 3)            wt += sar[nb][p - nb * Ss];
        swt[p] = wt;
    }
    if (tid == 0) soff = 0.25f * (s2red[0] + s2red[1] + s2red[2] + s2red[3]);
    __syncthreads();

    // ---- pass 2: combined weighted feature sum (cache-warm re-read) ----
    {
        int g = tid >> 7, c4 = tid & 127;
        const float4* f4 = (const float4*)fbase;
        float4 acc = make_float4(0.f, 0.f, 0.f, 0.f);
#pragma unroll 4
        for (int p = g; p < Pp; p += 4) {
            float wt = swt[p];
            float4 v = f4[p * 128 + c4];
            acc.x = fmaf(wt, v.x, acc.x);
            acc.y = fmaf(wt, v.y, acc.y);
            acc.z = fmaf(wt, v.z, acc.z);
            acc.w = fmaf(wt, v.w, acc.w);
        }
        *(float4*)&spart[g][c4 * 4] = acc;
    }
    __syncthreads();
    fm_s[tid] = 0.25f * (spart[0][tid] + spart[1][tid] + spart[2][tid] + spart[3][tid]) - soff;
    __syncthreads();

    // ---- tail: out = fm_s @ WvoT + bo (coalesced, L2-resident WvoT) ----
    {
        int cq = (tid & 127) * 4, h = tid >> 7;     // 4 e-groups of 128
        float4 acc = make_float4(0.f, 0.f, 0.f, 0.f);
#pragma unroll 4
        for (int e = h * 128; e < h * 128 + 128; ++e) {
            float fe = fm_s[e];
            float4 w = *(const float4*)&WvoT[(size_t)e * Dd + cq];
            acc.x = fmaf(fe, w.x, acc.x);
            acc.y = fmaf(fe, w.y, acc.y);
            acc.z = fmaf(fe, w.z, acc.z);
            acc.w = fmaf(fe, w.w, acc.w);
        }
        *(float4*)&spart[h][cq] = acc;
    }
    __syncthreads();
    out[(size_t)bx * Dd + tid] = bo[tid]
        + spart[0][tid] + spart[1][tid] + spart[2][tid] + spart[3][tid];
}

// ---------------------------------------------------------------------------
extern "C" void kernel_launch(void* const* d_in, const int* in_sizes, int n_in,
                              void* d_out, int out_size, void* d_ws, size_t ws_size,
                              hipStream_t stream) {
    const float* feats  = (const float*)d_in[0];
    const float* coords = (const float*)d_in[1];
    // d_in[2] = mask, unused (all false, and unused by the reference body)
    const float* z  = (const float*)d_in[3];
    const float* Wq = (const float*)d_in[4];
    const float* Wk = (const float*)d_in[5];
    const float* Wv = (const float*)d_in[6];
    const float* W1 = (const float*)d_in[7];
    const float* b1 = (const float*)d_in[8];
    const float* W2 = (const float*)d_in[9];
    const float* b2 = (const float*)d_in[10];
    const float* Wo = (const float*)d_in[11];
    const float* bo = (const float*)d_in[12];
    float* out = (float*)d_out;

    // workspace layout (floats) — nothing needs pre-zeroing
    float* ws = (float*)d_ws;
    float* cstats = ws;                         // 16
    float* QK     = ws + 16;                    // 64*512
    float* G      = QK + Ll * Dd;               // 64*512
    float* sqk4   = G + Ll * Dd;                // 256 (4 chunk-partials x 64)
    float* qb2    = sqk4 + 256;                 // 64
    float* WvoT   = qb2 + Ll;                   // 512*512

    pre_k<<<388, 256, 0, stream>>>(coords, z, Wq, Wk, W2, b2, Wv, Wo,
                                   cstats, QK, G, sqk4, qb2, WvoT);

    attn2<<<Bz * Ll, 512, 0, stream>>>(feats, coords, cstats,
                                       QK, G, sqk4, qb2, W1, b1,
                                       WvoT, bo, out);
}